// Round 1
// baseline (585.606 us; speedup 1.0000x reference)
//
#include <hip/hip_runtime.h>

// out = ((1 + cos)/2 + 1e-8)/0.05 = 10*cos + 10 (+2e-7, below f32 ulp at 10)
// cos = normalize(emb) @ normalize(weight)^T
// emb: 65536x768 f32, weight: 1024x768 f32, out: 65536x1024 f32

#define N_EMB 65536
#define N_W   1024
#define DIM   768
#define NKT   (DIM / 64)   // 12 K-tiles of BK=64

typedef __attribute__((ext_vector_type(4))) float f32x4;
typedef __attribute__((ext_vector_type(8))) __bf16 bf16x8;

__device__ __forceinline__ unsigned short f2bf(float x) {
    unsigned int u = __float_as_uint(x);
    u += 0x7FFF + ((u >> 16) & 1);      // round-to-nearest-even
    return (unsigned short)(u >> 16);
}

// One wave per row: L2-normalize + cast to bf16.
__global__ __launch_bounds__(256) void norm_cast_kernel(
    const float* __restrict__ emb, const float* __restrict__ weight,
    unsigned short* __restrict__ A, unsigned short* __restrict__ B)
{
    const int wave = threadIdx.x >> 6;
    const int lane = threadIdx.x & 63;
    int row = blockIdx.x * 4 + wave;
    const float* src;
    unsigned short* dst;
    if (row < N_EMB) {
        src = emb + (size_t)row * DIM;
        dst = A + (size_t)row * DIM;
    } else {
        int r = row - N_EMB;
        src = weight + (size_t)r * DIM;
        dst = B + (size_t)r * DIM;
    }
    const float4* s4 = (const float4*)src;
    float4 v[3];
    float ss = 0.f;
#pragma unroll
    for (int i = 0; i < 3; i++) {
        v[i] = s4[lane + 64 * i];
        ss += v[i].x * v[i].x + v[i].y * v[i].y + v[i].z * v[i].z + v[i].w * v[i].w;
    }
#pragma unroll
    for (int off = 32; off > 0; off >>= 1) ss += __shfl_xor(ss, off);
    float scale = 1.0f / fmaxf(sqrtf(ss), 1e-8f);
    ushort4* d4 = (ushort4*)dst;
#pragma unroll
    for (int i = 0; i < 3; i++) {
        ushort4 o;
        o.x = f2bf(v[i].x * scale);
        o.y = f2bf(v[i].y * scale);
        o.z = f2bf(v[i].z * scale);
        o.w = f2bf(v[i].w * scale);
        d4[lane + 64 * i] = o;
    }
}

__device__ __forceinline__ void async16(const void* g, void* l) {
    __builtin_amdgcn_global_load_lds(
        (const __attribute__((address_space(1))) void*)g,
        (__attribute__((address_space(3))) void*)l, 16, 0, 0);
}

// Raw barrier / waitcnt: compiler memory fences but NO vmcnt(0) drain
// (that drain is what capped the old 2-barrier structure at 437 TF).
#define BAR()    asm volatile("s_barrier" ::: "memory")
#define LGKM0()  asm volatile("s_waitcnt lgkmcnt(0)" ::: "memory")
#define VMCNT(n) asm volatile("s_waitcnt vmcnt(" #n ")" ::: "memory")
#define SCHED0() __builtin_amdgcn_sched_barrier(0)

// Stage one half-tile (128 rows-equivalent = 16KB) of K-tile kt, K-half h
// into LDS buffer Ls. 2 x global_load_lds(16B) per thread, 512 threads.
// LDS slot (h*1024 + ko_local*256 + m) holds X[m][kt*64 + h*32 + ko_local*8 ..+8].
// Dest is linear in t (wave-uniform base + lane*16) as global_load_lds requires.
__device__ __forceinline__ void stage_half(const unsigned short* Gp, bf16x8* Ls,
                                           int kt, int h, int t) {
    const int ke = kt * 64 + h * 32;
    async16(Gp + ke,      &Ls[h * 1024 + t]);
    async16(Gp + ke + 16, &Ls[h * 1024 + 512 + t]);
}

// One K-tile (BK=64) = 4 phases. Phase = (k-half, row-half of wave tile),
// 16 MFMA each. Staging: P1->A-k1(t+1), P2->B-k1(t+1), P3->A-k0(t+2),
// P4->B-k0(t+2); each target region's readers finished at the previous
// phase's closing barrier. vmcnt(8) before the closing barriers of P2/P4
// forces only the oldest in-flight half-tile pair to land (12 loads max in
// flight, 8 stay in flight across the barrier -> T4 counted-vmcnt pipeline).
__device__ __forceinline__ void ktile(
    bf16x8* Ac, bf16x8* Bc, bf16x8* An, bf16x8* Bn,
    int kt1, int kt2,
    const unsigned short* Ag, const unsigned short* Bg, int t,
    int aoff0, int boff0, f32x4 (&acc)[8][4])
{
    bf16x8 aLo[4], aHi[4], bb[4];
    // ---- P1: k-half 0, rows 0-63 of wave tile ----
#pragma unroll
    for (int i = 0; i < 4; ++i) aLo[i] = Ac[aoff0 + i * 16];
#pragma unroll
    for (int j = 0; j < 4; ++j) bb[j]  = Bc[boff0 + j * 16];
    stage_half(Ag, An, kt1, 1, t);
    BAR(); LGKM0();
    __builtin_amdgcn_s_setprio(1);
#pragma unroll
    for (int i = 0; i < 4; ++i)
#pragma unroll
        for (int j = 0; j < 4; ++j)
            acc[i][j] = __builtin_amdgcn_mfma_f32_16x16x32_bf16(aLo[i], bb[j], acc[i][j], 0, 0, 0);
    __builtin_amdgcn_s_setprio(0);
    SCHED0(); BAR();
    // ---- P2: k-half 0, rows 64-127 (reuse bb) ----
#pragma unroll
    for (int i = 0; i < 4; ++i) aHi[i] = Ac[aoff0 + 64 + i * 16];
    stage_half(Bg, Bn, kt1, 1, t);
    BAR(); LGKM0();
    __builtin_amdgcn_s_setprio(1);
#pragma unroll
    for (int i = 0; i < 4; ++i)
#pragma unroll
        for (int j = 0; j < 4; ++j)
            acc[4 + i][j] = __builtin_amdgcn_mfma_f32_16x16x32_bf16(aHi[i], bb[j], acc[4 + i][j], 0, 0, 0);
    __builtin_amdgcn_s_setprio(0);
    SCHED0();
    VMCNT(8); BAR();          // A-k1/B-k1 of this K-tile have landed
    // ---- P3: k-half 1, rows 0-63 ----
#pragma unroll
    for (int i = 0; i < 4; ++i) aLo[i] = Ac[1024 + aoff0 + i * 16];
#pragma unroll
    for (int j = 0; j < 4; ++j) bb[j]  = Bc[1024 + boff0 + j * 16];
    stage_half(Ag, Ac, kt2, 0, t);   // overwrites A-k0, last read in P2
    BAR(); LGKM0();
    __builtin_amdgcn_s_setprio(1);
#pragma unroll
    for (int i = 0; i < 4; ++i)
#pragma unroll
        for (int j = 0; j < 4; ++j)
            acc[i][j] = __builtin_amdgcn_mfma_f32_16x16x32_bf16(aLo[i], bb[j], acc[i][j], 0, 0, 0);
    __builtin_amdgcn_s_setprio(0);
    SCHED0(); BAR();
    // ---- P4: k-half 1, rows 64-127 ----
#pragma unroll
    for (int i = 0; i < 4; ++i) aHi[i] = Ac[1024 + aoff0 + 64 + i * 16];
    stage_half(Bg, Bc, kt2, 0, t);   // overwrites B-k0, last read in P1
    BAR(); LGKM0();
    __builtin_amdgcn_s_setprio(1);
#pragma unroll
    for (int i = 0; i < 4; ++i)
#pragma unroll
        for (int j = 0; j < 4; ++j)
            acc[4 + i][j] = __builtin_amdgcn_mfma_f32_16x16x32_bf16(aHi[i], bb[j], acc[4 + i][j], 0, 0, 0);
    __builtin_amdgcn_s_setprio(0);
    SCHED0();
    VMCNT(8); BAR();          // A-k0/B-k0 of next K-tile have landed
}

// C[M=65536, N=1024] = A[M,768] @ B[N,768]^T, bf16, 256x256 tile, BK=64,
// 512 threads = 8 waves (2 row-groups x 4 col-groups), each wave 128x64 out
// via 8x4 grid of 16x16x32 MFMAs. 128 KiB LDS double buffer, deep-pipelined
// 4-phase schedule with counted vmcnt (never 0 in the main loop).
__global__ __launch_bounds__(512, 2) void cos_gemm_kernel(
    const unsigned short* __restrict__ A, const unsigned short* __restrict__ B,
    float* __restrict__ out)
{
    __shared__ bf16x8 As[2][2048];   // [buf][ khalf*1024 + ko*256 + m ]  64KB
    __shared__ bf16x8 Bs[2][2048];   // same layout for the 256 B-rows     64KB

    const int t = threadIdx.x;
    const int l16 = t & 15, quad = (t >> 4) & 3;
    const int wave = t >> 6, wm = wave >> 2, wn = wave & 3;

    // XCD swizzle: each XCD gets 32 row-tiles x 4 col-tiles consecutively ->
    // 384KB A-panel + all of B (1.5MB) stay resident in its 4MB L2.
    const int b = blockIdx.x;           // 0..1023
    const int xcd = b & 7, s = b >> 3;  // s: 0..127
    const int row0 = (xcd * 32 + (s >> 2)) * 256;
    const int col0 = (s & 3) * 256;

    // Per-thread global staging addresses: row = t&255, ko_local base = t>>8.
    const unsigned short* Ag = A + (size_t)(row0 + (t & 255)) * DIM + ((t >> 8) * 8);
    const unsigned short* Bg = B + (size_t)(col0 + (t & 255)) * DIM + ((t >> 8) * 8);

    bf16x8* As0 = &As[0][0]; bf16x8* Bs0 = &Bs[0][0];
    bf16x8* As1 = &As[1][0]; bf16x8* Bs1 = &Bs[1][0];

    // Fragment read offsets: slot = khalf*1024 + (quad)*256 + m, m = frag row.
    // 16 lanes (l16) read 16 consecutive 16B slots -> conflict-free ds_read_b128.
    const int aoff0 = quad * 256 + wm * 128 + l16;
    const int boff0 = quad * 256 + wn * 64 + l16;

    f32x4 acc[8][4] = {};

    // Prologue: 6 half-tiles = 12 loads in flight; wait the oldest pair only.
    stage_half(Ag, As0, 0, 0, t); stage_half(Bg, Bs0, 0, 0, t);
    stage_half(Ag, As0, 0, 1, t); stage_half(Bg, Bs0, 0, 1, t);
    stage_half(Ag, As1, 1, 0, t); stage_half(Bg, Bs1, 1, 0, t);
    VMCNT(8); BAR();

#pragma unroll 1
    for (int kt = 0; kt < NKT; kt += 2) {
        int k1 = kt + 1;                       // always < NKT (kt <= NKT-2)
        int k2 = kt + 2; if (k2 >= NKT) k2 = 0;   // tail: dummy re-stage of
        int k3 = kt + 3; if (k3 >= NKT) k3 = 0;   // tile 0 keeps vmcnt uniform
        ktile(As0, Bs0, As1, Bs1, k1, k2, Ag, Bg, t, aoff0, boff0, acc);
        ktile(As1, Bs1, As0, Bs0, k2, k3, Ag, Bg, t, aoff0, boff0, acc);
    }
    VMCNT(0);   // drain tail prefetches before kernel end

    // C/D layout: col = l16, row = quad*4 + reg. Non-temporal: C is
    // write-once; keep it out of L2 so the A panel and B stay resident.
#pragma unroll
    for (int i = 0; i < 8; ++i) {
#pragma unroll
        for (int r = 0; r < 4; ++r) {
            int row = row0 + wm * 128 + i * 16 + quad * 4 + r;
            float* orow = out + (size_t)row * N_W + col0 + wn * 64 + l16;
#pragma unroll
            for (int j = 0; j < 4; ++j)
                __builtin_nontemporal_store(fmaf(acc[i][j][r], 10.0f, 10.0f), orow + j * 16);
        }
    }
}

extern "C" void kernel_launch(void* const* d_in, const int* in_sizes, int n_in,
                              void* d_out, int out_size, void* d_ws, size_t ws_size,
                              hipStream_t stream) {
    const float* emb    = (const float*)d_in[0];
    const float* weight = (const float*)d_in[1];
    unsigned short* A = (unsigned short*)d_ws;                       // 65536*768 bf16
    unsigned short* B = A + (size_t)N_EMB * DIM;                     // 1024*768 bf16
    float* out = (float*)d_out;

    norm_cast_kernel<<<(N_EMB + N_W) / 4, 256, 0, stream>>>(emb, weight, A, B);
    cos_gemm_kernel<<<1024, 512, 0, stream>>>(A, B, out);
}

// Round 2
// 506.879 us; speedup vs baseline: 1.1553x; 1.1553x over previous
//
#include <hip/hip_runtime.h>

// out = ((1 + cos)/2 + 1e-8)/0.05 = 10*cos + 10 (+2e-7, below f32 ulp at 10)
// cos = normalize(emb) @ normalize(weight)^T
// emb: 65536x768 f32, weight: 1024x768 f32, out: 65536x1024 f32

#define N_EMB 65536
#define N_W   1024
#define DIM   768
#define NKT   (DIM / 64)   // 12 K-tiles of BK=64

typedef __attribute__((ext_vector_type(4))) float f32x4;
typedef __attribute__((ext_vector_type(8))) __bf16 bf16x8;

__device__ __forceinline__ unsigned short f2bf(float x) {
    unsigned int u = __float_as_uint(x);
    u += 0x7FFF + ((u >> 16) & 1);      // round-to-nearest-even
    return (unsigned short)(u >> 16);
}

// One wave per row: L2-normalize + cast to bf16.
__global__ __launch_bounds__(256) void norm_cast_kernel(
    const float* __restrict__ emb, const float* __restrict__ weight,
    unsigned short* __restrict__ A, unsigned short* __restrict__ B)
{
    const int wave = threadIdx.x >> 6;
    const int lane = threadIdx.x & 63;
    int row = blockIdx.x * 4 + wave;
    const float* src;
    unsigned short* dst;
    if (row < N_EMB) {
        src = emb + (size_t)row * DIM;
        dst = A + (size_t)row * DIM;
    } else {
        int r = row - N_EMB;
        src = weight + (size_t)r * DIM;
        dst = B + (size_t)r * DIM;
    }
    const float4* s4 = (const float4*)src;
    float4 v[3];
    float ss = 0.f;
#pragma unroll
    for (int i = 0; i < 3; i++) {
        v[i] = s4[lane + 64 * i];
        ss += v[i].x * v[i].x + v[i].y * v[i].y + v[i].z * v[i].z + v[i].w * v[i].w;
    }
#pragma unroll
    for (int off = 32; off > 0; off >>= 1) ss += __shfl_xor(ss, off);
    float scale = 1.0f / fmaxf(sqrtf(ss), 1e-8f);
    ushort4* d4 = (ushort4*)dst;
#pragma unroll
    for (int i = 0; i < 3; i++) {
        ushort4 o;
        o.x = f2bf(v[i].x * scale);
        o.y = f2bf(v[i].y * scale);
        o.z = f2bf(v[i].z * scale);
        o.w = f2bf(v[i].w * scale);
        d4[lane + 64 * i] = o;
    }
}

__device__ __forceinline__ void async16(const void* g, void* l) {
    __builtin_amdgcn_global_load_lds(
        (const __attribute__((address_space(1))) void*)g,
        (__attribute__((address_space(3))) void*)l, 16, 0, 0);
}

#define BAR()    __builtin_amdgcn_s_barrier()
#define LGKM0()  asm volatile("s_waitcnt lgkmcnt(0)" ::: "memory")
#define VMCNT(n) asm volatile("s_waitcnt vmcnt(" #n ")" ::: "memory")
#define SCHED0() __builtin_amdgcn_sched_barrier(0)

// ---------------------------------------------------------------------------
// GEMM: C[65536,1024] = A @ B^T, bf16, 256x256 tile, BK=64, 512 thr / 8 waves
// (2 wm x 4 wn), wave tile 128x64 = 8x4 grid of 16x16x32 MFMAs.
//
// LDS: per matrix, per buffer: 2 "quarter" planes of [128 rows'][64 k] bf16
// (row-major, 128B rows). Row' permutation packs exactly the rows a C-quadrant
// phase reads:  A: row' = ih*128 + wm*64 + i2*16 + r16  <->  grow = wm*128+ih*64+i2*16+r16
//               B: row' = jh*128 + wn*32 + j2*16 + r16  <->  gcol = wn*64+jh*32+j2*16+r16
// Bank swizzle (G4): chunk' = chunk ^ (row'&7). Staging keeps the LDS dest
// LINEAR in t (global_load_lds requirement) and pre-swizzles the *global*
// source chunk: thread t covers row' = t>>3 (+64*ld), chunk t&7, source
// k-chunk (t&7)^((t>>3)&7). 8 consecutive threads read one full 128B line ->
// coalesced (vs 64 scattered lines/instr in the previous layout, which was
// the 3000-cyc/phase bottleneck).
//
// Schedule (4 C-quadrant phases per K-tile, stage tile t+1 into other buffer):
//   P1 (ih0,jh0): read 8A+4B, stage Aq0(t+1) | P2 (ih0,jh1): read 4B, stage Bq0
//   P3 (ih1,jh0): read 8A,    stage Bq1      | P4 (ih1,jh1): read 0,  stage Aq1
// VMCNT(4) per phase (P3: VMCNT(6)) -> 2-phase landing slack, never vmcnt(0)
// in the main loop (T3+T4 counted-vmcnt pipeline).
// ---------------------------------------------------------------------------

__device__ __forceinline__ void ktile(
    const bf16x8* Ac, const bf16x8* Bc,   // current-tile buffers
    bf16x8* An, bf16x8* Bn,               // next-tile buffers (stage dest)
    int ktn,                              // K-tile index to stage
    const unsigned short* AgT, const unsigned short* BgT,
    int t, int abase, int bbase, int quad, int axor,
    f32x4 (&acc)[8][4])
{
    bf16x8 a[4][2], b0[2][2], b1[2][2];
    const int c0 = (0 * 4 + quad) ^ axor;   // swizzled chunk, kk=0
    const int c1 = (1 * 4 + quad) ^ axor;   // swizzled chunk, kk=1
    const int ko = ktn * 64;

    // ---- P1: quadrant (ih=0, jh=0) ----
#pragma unroll
    for (int i2 = 0; i2 < 4; ++i2) {
        a[i2][0] = Ac[i2 * 128 + abase + c0];
        a[i2][1] = Ac[i2 * 128 + abase + c1];
    }
#pragma unroll
    for (int j2 = 0; j2 < 2; ++j2) {
        b0[j2][0] = Bc[j2 * 128 + bbase + c0];
        b0[j2][1] = Bc[j2 * 128 + bbase + c1];
    }
    async16(AgT + ko,                    &An[t]);        // Aq0: rows' 0-63
    async16(AgT + (size_t)128 * DIM + ko, &An[512 + t]); //      rows' 64-127
    BAR(); LGKM0();
    __builtin_amdgcn_s_setprio(1);
#pragma unroll
    for (int i2 = 0; i2 < 4; ++i2)
#pragma unroll
        for (int j2 = 0; j2 < 2; ++j2)
#pragma unroll
            for (int kk = 0; kk < 2; ++kk)
                acc[i2][j2] = __builtin_amdgcn_mfma_f32_16x16x32_bf16(a[i2][kk], b0[j2][kk], acc[i2][j2], 0, 0, 0);
    __builtin_amdgcn_s_setprio(0);
    SCHED0();
    VMCNT(4); BAR();

    // ---- P2: quadrant (ih=0, jh=1) ----
#pragma unroll
    for (int j2 = 0; j2 < 2; ++j2) {
        b1[j2][0] = Bc[1024 + j2 * 128 + bbase + c0];
        b1[j2][1] = Bc[1024 + j2 * 128 + bbase + c1];
    }
    async16(BgT + ko,                    &Bn[t]);        // Bq0
    async16(BgT + (size_t)128 * DIM + ko, &Bn[512 + t]);
    BAR(); LGKM0();
    __builtin_amdgcn_s_setprio(1);
#pragma unroll
    for (int i2 = 0; i2 < 4; ++i2)
#pragma unroll
        for (int j2 = 0; j2 < 2; ++j2)
#pragma unroll
            for (int kk = 0; kk < 2; ++kk)
                acc[i2][2 + j2] = __builtin_amdgcn_mfma_f32_16x16x32_bf16(a[i2][kk], b1[j2][kk], acc[i2][2 + j2], 0, 0, 0);
    __builtin_amdgcn_s_setprio(0);
    SCHED0();
    VMCNT(4); BAR();

    // ---- P3: quadrant (ih=1, jh=0) ----
#pragma unroll
    for (int i2 = 0; i2 < 4; ++i2) {
        a[i2][0] = Ac[1024 + i2 * 128 + abase + c0];
        a[i2][1] = Ac[1024 + i2 * 128 + abase + c1];
    }
    async16(BgT + (size_t)32 * DIM + ko,  &Bn[1024 + t]);  // Bq1
    async16(BgT + (size_t)160 * DIM + ko, &Bn[1536 + t]);
    BAR(); LGKM0();
    __builtin_amdgcn_s_setprio(1);
#pragma unroll
    for (int i2 = 0; i2 < 4; ++i2)
#pragma unroll
        for (int j2 = 0; j2 < 2; ++j2)
#pragma unroll
            for (int kk = 0; kk < 2; ++kk)
                acc[4 + i2][j2] = __builtin_amdgcn_mfma_f32_16x16x32_bf16(a[i2][kk], b0[j2][kk], acc[4 + i2][j2], 0, 0, 0);
    __builtin_amdgcn_s_setprio(0);
    SCHED0();
    VMCNT(6); BAR();   // nothing needed before P4's MFMAs; keep pipeline deep

    // ---- P4: quadrant (ih=1, jh=1), no ds_reads ----
    async16(AgT + (size_t)64 * DIM + ko,  &An[1024 + t]);  // Aq1
    async16(AgT + (size_t)192 * DIM + ko, &An[1536 + t]);
    BAR();
    __builtin_amdgcn_s_setprio(1);
#pragma unroll
    for (int i2 = 0; i2 < 4; ++i2)
#pragma unroll
        for (int j2 = 0; j2 < 2; ++j2)
#pragma unroll
            for (int kk = 0; kk < 2; ++kk)
                acc[4 + i2][2 + j2] = __builtin_amdgcn_mfma_f32_16x16x32_bf16(a[i2][kk], b1[j2][kk], acc[4 + i2][2 + j2], 0, 0, 0);
    __builtin_amdgcn_s_setprio(0);
    SCHED0();
    VMCNT(4); BAR();   // Aq0/Bq0 of tile t+1 have landed -> next P1 reads OK
}

__global__ __launch_bounds__(512, 2) void cos_gemm_kernel(
    const unsigned short* __restrict__ A, const unsigned short* __restrict__ B,
    float* __restrict__ out)
{
    __shared__ bf16x8 As[2][2048];   // [buf][ih*1024 + row'*8 + chunk]  64KB
    __shared__ bf16x8 Bs[2][2048];   // [buf][jh*1024 + row'*8 + chunk]  64KB

    const int t = threadIdx.x;
    const int lane = t & 63;
    const int l16 = t & 15, quad = (t >> 4) & 3;
    const int wave = t >> 6, wm = wave >> 2, wn = wave & 3;

    // XCD swizzle: each XCD gets 32 row-tiles x 4 col-tiles consecutively ->
    // 384KB A-panel + all of B (1.5MB) stay resident in its 4MB L2.
    const int b = blockIdx.x;           // 0..1023
    const int xcd = b & 7, s = b >> 3;  // s: 0..127
    const int row0 = (xcd * 32 + (s >> 2)) * 256;
    const int col0 = (s & 3) * 256;

    // Staging source (pre-swizzled): thread t covers LDS row' r64=t>>3 (+64*ld),
    // chunk t&7; must load global k-chunk (t&7)^(r64&7).
    const int r64 = t >> 3;
    const int cSrc = (t & 7) ^ (r64 & 7);
    // A: grow(row') = ld*128 + ih*64 + r64
    const unsigned short* AgT = A + (size_t)(row0 + r64) * DIM + cSrc * 8;
    // B: gcol(row') = ld*128 + (r64>>5)*64 + jh*32 + (r64&31)
    const unsigned short* BgT = B + (size_t)(col0 + (r64 >> 5) * 64 + (r64 & 31)) * DIM + cSrc * 8;

    // Fragment read slot bases (slot = plane*1024 + row'*8 + chunk')
    const int axor  = lane & 7;
    const int abase = wm * 512 + l16 * 8;   // + ih*1024 + i2*128 + chunk'
    const int bbase = wn * 256 + l16 * 8;   // + jh*1024 + j2*128 + chunk'

    f32x4 acc[8][4] = {};

    // Prologue: stage all 4 quarters of tile 0 into buf 0, in consumption order.
    async16(AgT,                      &As[0][t]);          // Aq0
    async16(AgT + (size_t)128 * DIM,  &As[0][512 + t]);
    async16(BgT,                      &Bs[0][t]);          // Bq0
    async16(BgT + (size_t)128 * DIM,  &Bs[0][512 + t]);
    async16(BgT + (size_t)32 * DIM,   &Bs[0][1024 + t]);   // Bq1
    async16(BgT + (size_t)160 * DIM,  &Bs[0][1536 + t]);
    async16(AgT + (size_t)64 * DIM,   &As[0][1024 + t]);   // Aq1
    async16(AgT + (size_t)192 * DIM,  &As[0][1536 + t]);
    VMCNT(4); BAR();   // Aq0+Bq0 landed; Bq1/Aq1 still in flight

#pragma unroll 1
    for (int kt = 0; kt < NKT; ++kt) {
        const int cur = kt & 1;
        int ktn = kt + 1; if (ktn == NKT) ktn = 0;   // tail: dummy re-stage keeps
        ktile(&As[cur][0], &Bs[cur][0],              // vmcnt counts uniform
              &As[cur ^ 1][0], &Bs[cur ^ 1][0],
              ktn, AgT, BgT, t, abase, bbase, quad, axor, acc);
    }
    VMCNT(0);   // drain tail dummy prefetches before epilogue/exit

    // C/D layout: col = l16, row = quad*4 + reg; acc[i = ih*4+i2][j = jh*2+j2].
    // Non-temporal: C is write-once; keep it out of L2 so A/B stay resident.
#pragma unroll
    for (int i = 0; i < 8; ++i) {
#pragma unroll
        for (int r = 0; r < 4; ++r) {
            int row = row0 + wm * 128 + i * 16 + quad * 4 + r;
            float* orow = out + (size_t)row * N_W + col0 + wn * 64 + l16;
#pragma unroll
            for (int j = 0; j < 4; ++j)
                __builtin_nontemporal_store(fmaf(acc[i][j][r], 10.0f, 10.0f), orow + j * 16);
        }
    }
}

extern "C" void kernel_launch(void* const* d_in, const int* in_sizes, int n_in,
                              void* d_out, int out_size, void* d_ws, size_t ws_size,
                              hipStream_t stream) {
    const float* emb    = (const float*)d_in[0];
    const float* weight = (const float*)d_in[1];
    unsigned short* A = (unsigned short*)d_ws;                       // 65536*768 bf16
    unsigned short* B = A + (size_t)N_EMB * DIM;                     // 1024*768 bf16
    float* out = (float*)d_out;

    norm_cast_kernel<<<(N_EMB + N_W) / 4, 256, 0, stream>>>(emb, weight, A, B);
    cos_gemm_kernel<<<1024, 512, 0, stream>>>(A, B, out);
}